// Round 5
// baseline (365.448 us; speedup 1.0000x reference)
//
#include <hip/hip_runtime.h>
#include <hip/hip_bf16.h>

// Problem constants
#define BATCH   2048
#define IN_CH   12
#define UPLAG   2048
#define STEP    4
#define FEAT    512              // UPLAG/STEP
#define DIN     6144             // IN_CH*FEAT
#define HIDDEN  1024
#define OUTPUT  256

typedef __bf16 bf16x8 __attribute__((ext_vector_type(8)));
typedef float  f32x4  __attribute__((ext_vector_type(4)));

__device__ __forceinline__ unsigned short f2bf(float f) {
  unsigned int u = __builtin_bit_cast(unsigned int, f);
  unsigned int r = (u + 0x7fffu + ((u >> 16) & 1u)) >> 16;   // RNE
  return (unsigned short)r;
}

__device__ __forceinline__ float bf2f(unsigned short h) {
  unsigned int u = ((unsigned int)h) << 16;
  return __builtin_bit_cast(float, u);
}

__device__ __forceinline__ void async_copy16(const unsigned short* g, unsigned short* l) {
  __builtin_amdgcn_global_load_lds(
      (const __attribute__((address_space(1))) unsigned int*)g,
      (__attribute__((address_space(3))) unsigned int*)l, 16, 0, 0);
}

// ---------------------------------------------------------------------------
// Kernel 1 (fused prep): sectioned grid.
//   blocks [0, 4096)        : conv+cast, grid-stride (12 iters/thread)
//   blocks [4096, 5632)     : W2 transpose-cast, 64x64 tiles
//   blocks [5632, 5696)     : W3 transpose-cast, 64x64 tiles
// ---------------------------------------------------------------------------
#define CONV_BLOCKS 4096
#define W2T_BLOCKS  1536   // (1024/64) x (6144/64) = 16 x 96
#define W3T_BLOCKS  64     // (256/64)  x (1024/64) =  4 x 16

__global__ __launch_bounds__(256) void prep_kernel(
    const float* __restrict__ x, const float* __restrict__ W1,
    const float* __restrict__ b1, unsigned short* __restrict__ flatA,
    const float* __restrict__ W2, unsigned short* __restrict__ W2T,
    const float* __restrict__ W3, unsigned short* __restrict__ W3T)
{
  __shared__ float tile[64][65];
  const int t = threadIdx.x;
  int b = blockIdx.x;

  if (b < CONV_BLOCKS) {
    const int total = BATCH * DIN;
    for (int gid = b * 256 + t; gid < total; gid += CONV_BLOCKS * 256) {
      int cf = gid % DIN;          // c*FEAT + f
      int c  = cf >> 9;            // /512
      float4 xv = ((const float4*)x)[gid];
      float4 wv = ((const float4*)W1)[c];
      float v = xv.x * wv.x + xv.y * wv.y + xv.z * wv.z + xv.w * wv.w + b1[c];
      flatA[gid] = f2bf(v);
    }
    return;
  }

  const float* in; unsigned short* outp; int R, Ncol, bx, by;
  if (b < CONV_BLOCKS + W2T_BLOCKS) {
    int idx = b - CONV_BLOCKS;
    in = W2; outp = W2T; R = DIN; Ncol = HIDDEN;
    bx = (idx & 15) * 64; by = (idx >> 4) * 64;
  } else {
    int idx = b - CONV_BLOCKS - W2T_BLOCKS;
    in = W3; outp = W3T; R = HIDDEN; Ncol = OUTPUT;
    bx = (idx & 3) * 64; by = (idx >> 2) * 64;
  }
  int tx = t & 63, ty = t >> 6;     // 4 rows per pass
  #pragma unroll
  for (int i = 0; i < 64; i += 4)
    tile[ty + i][tx] = in[(size_t)(by + ty + i) * Ncol + bx + tx];
  __syncthreads();
  #pragma unroll
  for (int i = 0; i < 64; i += 4)
    outp[(size_t)(bx + ty + i) * R + by + tx] = f2bf(tile[tx][ty + i]);
}

// ---------------------------------------------------------------------------
// Kernel 2: GEMM1, split-K=6, XCD swizzle, BK=64, XOR-swizzled LDS layout.
// (unchanged from R4)
// ---------------------------------------------------------------------------
#define G1_BM 128
#define G1_BN 128
#define G1_BK 64
#define SPLITK 6

__global__ __launch_bounds__(256, 2) void gemm1_kernel(
    const unsigned short* __restrict__ A,   // [M,K]
    const unsigned short* __restrict__ BT,  // [N,K]
    unsigned short* __restrict__ Cp,        // [SPLITK, M, N] bf16
    int M, int N, int K)
{
  __shared__ unsigned short As[G1_BM * G1_BK];   // 16 KB
  __shared__ unsigned short Bs[G1_BN * G1_BK];   // 16 KB
  const int t    = threadIdx.x;
  const int lane = t & 63;
  const int wave = t >> 6;

  int b    = blockIdx.x;
  int xcdg = b & 7;
  int rest = b >> 3;          // 0..95
  int xt   = rest & 7;        // n-tile 0..7
  int zz   = rest >> 3;       // 0..11
  int zt   = zz >> 1;         // k-slice 0..5
  int yt   = (xcdg << 1) | (zz & 1);  // m-tile 0..15

  const int m0 = yt * G1_BM;
  const int n0 = xt * G1_BN;
  const int Ks = K / SPLITK;  // 1024
  const int kbeg = zt * Ks;

  const int wm = (wave >> 1) * 64;
  const int wn = (wave & 1) * 64;
  const int lm = lane & 15;
  const int kgrp = lane >> 4;          // 0..3

  f32x4 acc[4][4];
  #pragma unroll
  for (int i = 0; i < 4; i++)
    #pragma unroll
    for (int j = 0; j < 4; j++) {
      f32x4 z = {0.f, 0.f, 0.f, 0.f};
      acc[i][j] = z;
    }

  const unsigned short* Ag = A  + (size_t)m0 * K + kbeg;
  const unsigned short* Bg = BT + (size_t)n0 * K + kbeg;

  for (int kk = 0; kk < Ks; kk += G1_BK) {
    #pragma unroll
    for (int r = 0; r < 4; ++r) {
      int c = r * 256 + t;
      int row = c >> 3;
      int gk  = (c & 7) ^ (row & 7);
      async_copy16(Ag + (size_t)row * K + kk + gk * 8, As + c * 8);
    }
    #pragma unroll
    for (int r = 0; r < 4; ++r) {
      int c = r * 256 + t;
      int row = c >> 3;
      int gk  = (c & 7) ^ (row & 7);
      async_copy16(Bg + (size_t)row * K + kk + gk * 8, Bs + c * 8);
    }
    __syncthreads();

    #pragma unroll
    for (int s = 0; s < 2; ++s) {
      const int kch = kgrp + s * 4;
      bf16x8 af[4], bfr[4];
      #pragma unroll
      for (int i = 0; i < 4; i++) {
        int row = wm + i * 16 + lm;
        af[i] = *(const bf16x8*)(As + row * G1_BK + ((kch ^ (row & 7)) * 8));
      }
      #pragma unroll
      for (int j = 0; j < 4; j++) {
        int row = wn + j * 16 + lm;
        bfr[j] = *(const bf16x8*)(Bs + row * G1_BK + ((kch ^ (row & 7)) * 8));
      }
      #pragma unroll
      for (int i = 0; i < 4; i++)
        #pragma unroll
        for (int j = 0; j < 4; j++)
          acc[i][j] = __builtin_amdgcn_mfma_f32_16x16x32_bf16(af[i], bfr[j], acc[i][j], 0, 0, 0);
    }
    __syncthreads();
  }

  // epilogue: bf16 partials. C/D layout: col=lane&15, row=(lane>>4)*4+reg
  unsigned short* Co = Cp + (size_t)zt * M * N;
  const int rbase = kgrp * 4;
  #pragma unroll
  for (int i = 0; i < 4; i++)
    #pragma unroll
    for (int j = 0; j < 4; j++) {
      int col = n0 + wn + j * 16 + lm;
      #pragma unroll
      for (int r = 0; r < 4; r++) {
        int row = m0 + wm + i * 16 + rbase + r;
        Co[(size_t)row * N + col] = f2bf(acc[i][j][r]);
      }
    }
}

// ---------------------------------------------------------------------------
// Kernel 3 (fused tail): split-K reduce + b2 + ReLU -> LDS h-stripe,
// then h @ W3T + b3 -> out.  One block per 16-row M-stripe (128 blocks).
// Phase 2 reads W3T fragments straight from global (512 KB, L2-resident).
// LDS row stride HIDDEN+8 -> A-frag b128 reads are 2-way (free).
// ---------------------------------------------------------------------------
#define TB_M 16
#define HS_STRIDE (HIDDEN + 8)

__global__ __launch_bounds__(256) void tail_kernel(
    const unsigned short* __restrict__ Cp,   // [SPLITK][BATCH][HIDDEN] bf16
    const float* __restrict__ b2,
    const unsigned short* __restrict__ W3T,  // [OUTPUT][HIDDEN] bf16
    const float* __restrict__ b3,
    float* __restrict__ out)                 // [BATCH][OUTPUT] fp32
{
  __shared__ unsigned short hs[TB_M * HS_STRIDE];   // ~32.2 KB
  const int t = threadIdx.x;
  const int lane = t & 63;
  const int wave = t >> 6;
  const int m0 = blockIdx.x * TB_M;
  const int MN = BATCH * HIDDEN;

  // Phase 1: reduce 6 partials + bias + relu -> hs (bf16)
  for (int idx = t; idx < TB_M * (HIDDEN / 4); idx += 256) {
    int r  = idx >> 8;            // / (HIDDEN/4)
    int c4 = idx & 255;
    size_t base = (size_t)(m0 + r) * HIDDEN + c4 * 4;
    float4 s = *(const float4*)(b2 + c4 * 4);
    #pragma unroll
    for (int p = 0; p < SPLITK; ++p) {
      ushort4 a = *(const ushort4*)(Cp + (size_t)p * MN + base);
      s.x += bf2f(a.x); s.y += bf2f(a.y); s.z += bf2f(a.z); s.w += bf2f(a.w);
    }
    ushort4 o;
    o.x = f2bf(fmaxf(s.x, 0.f));
    o.y = f2bf(fmaxf(s.y, 0.f));
    o.z = f2bf(fmaxf(s.z, 0.f));
    o.w = f2bf(fmaxf(s.w, 0.f));
    *(ushort4*)(hs + r * HS_STRIDE + c4 * 4) = o;
  }
  __syncthreads();

  // Phase 2: hs[16][HIDDEN] @ W3T -> out rows m0..m0+15, cols wave*64..+63
  const int lm = lane & 15;
  const int kgrp = lane >> 4;          // 0..3
  const int ncol0 = wave * 64;
  f32x4 acc[4];
  #pragma unroll
  for (int j = 0; j < 4; j++) {
    f32x4 z = {0.f, 0.f, 0.f, 0.f};
    acc[j] = z;
  }

  #pragma unroll 2
  for (int kk = 0; kk < HIDDEN; kk += 32) {
    bf16x8 af = *(const bf16x8*)(hs + lm * HS_STRIDE + kk + kgrp * 8);
    #pragma unroll
    for (int j = 0; j < 4; j++) {
      const unsigned short* bp =
          W3T + (size_t)(ncol0 + j * 16 + lm) * HIDDEN + kk + kgrp * 8;
      bf16x8 bfr = *(const bf16x8*)bp;
      acc[j] = __builtin_amdgcn_mfma_f32_16x16x32_bf16(af, bfr, acc[j], 0, 0, 0);
    }
  }

  // epilogue: C/D layout col=lane&15, row=(lane>>4)*4+reg
  const int rbase = kgrp * 4;
  #pragma unroll
  for (int j = 0; j < 4; j++) {
    int col = ncol0 + j * 16 + lm;
    float bias = b3[col];
    #pragma unroll
    for (int r = 0; r < 4; r++) {
      int row = m0 + rbase + r;
      out[(size_t)row * OUTPUT + col] = acc[j][r] + bias;
    }
  }
}

// ---------------------------------------------------------------------------
extern "C" void kernel_launch(void* const* d_in, const int* in_sizes, int n_in,
                              void* d_out, int out_size, void* d_ws, size_t ws_size,
                              hipStream_t stream)
{
  const float* x  = (const float*)d_in[0];
  const float* W1 = (const float*)d_in[1];
  const float* b1 = (const float*)d_in[2];
  const float* W2 = (const float*)d_in[3];
  const float* b2 = (const float*)d_in[4];
  const float* W3 = (const float*)d_in[5];
  const float* b3 = (const float*)d_in[6];
  float* out = (float*)d_out;

  char* ws = (char*)d_ws;
  unsigned short* flatA = (unsigned short*)ws; ws += (size_t)BATCH * DIN * 2;
  unsigned short* W2T   = (unsigned short*)ws; ws += (size_t)HIDDEN * DIN * 2;
  unsigned short* W3T   = (unsigned short*)ws; ws += (size_t)OUTPUT * HIDDEN * 2;
  unsigned short* Cpart = (unsigned short*)ws; ws += (size_t)SPLITK * BATCH * HIDDEN * 2;

  // 1. fused prep: conv (grid-stride) + W2/W3 transpose-casts
  prep_kernel<<<CONV_BLOCKS + W2T_BLOCKS + W3T_BLOCKS, 256, 0, stream>>>(
      x, W1, b1, flatA, W2, W2T, W3, W3T);
  // 2. GEMM1 split-K=6, XCD swizzle, BK=64: 768 blocks
  gemm1_kernel<<<768, 256, 0, stream>>>(flatA, W2T, Cpart, BATCH, HIDDEN, DIN);
  // 3. fused tail: reduce + bias + relu + GEMM2 + bias -> out
  tail_kernel<<<BATCH / TB_M, 256, 0, stream>>>(Cpart, b2, W3T, b3, out);
}

// Round 6
// 359.935 us; speedup vs baseline: 1.0153x; 1.0153x over previous
//
#include <hip/hip_runtime.h>
#include <hip/hip_bf16.h>

// Problem constants
#define BATCH   2048
#define IN_CH   12
#define UPLAG   2048
#define STEP    4
#define FEAT    512              // UPLAG/STEP
#define DIN     6144             // IN_CH*FEAT
#define HIDDEN  1024
#define OUTPUT  256

typedef __bf16 bf16x8 __attribute__((ext_vector_type(8)));
typedef float  f32x4  __attribute__((ext_vector_type(4)));

__device__ __forceinline__ unsigned short f2bf(float f) {
  unsigned int u = __builtin_bit_cast(unsigned int, f);
  unsigned int r = (u + 0x7fffu + ((u >> 16) & 1u)) >> 16;   // RNE
  return (unsigned short)r;
}

__device__ __forceinline__ float bf2f(unsigned short h) {
  unsigned int u = ((unsigned int)h) << 16;
  return __builtin_bit_cast(float, u);
}

__device__ __forceinline__ void async_copy16(const unsigned short* g, unsigned short* l) {
  __builtin_amdgcn_global_load_lds(
      (const __attribute__((address_space(1))) unsigned int*)g,
      (__attribute__((address_space(3))) unsigned int*)l, 16, 0, 0);
}

// ---------------------------------------------------------------------------
// Kernel 1 (fused prep): sectioned grid.
//   blocks [0, 4096)        : conv+cast, grid-stride (12 iters/thread)
//   blocks [4096, 5632)     : W2 transpose-cast, 64x64 tiles
//   blocks [5632, 5696)     : W3 transpose-cast, 64x64 tiles
// ---------------------------------------------------------------------------
#define CONV_BLOCKS 4096
#define W2T_BLOCKS  1536   // (1024/64) x (6144/64) = 16 x 96
#define W3T_BLOCKS  64     // (256/64)  x (1024/64) =  4 x 16

__global__ __launch_bounds__(256) void prep_kernel(
    const float* __restrict__ x, const float* __restrict__ W1,
    const float* __restrict__ b1, unsigned short* __restrict__ flatA,
    const float* __restrict__ W2, unsigned short* __restrict__ W2T,
    const float* __restrict__ W3, unsigned short* __restrict__ W3T)
{
  __shared__ float tile[64][65];
  const int t = threadIdx.x;
  int b = blockIdx.x;

  if (b < CONV_BLOCKS) {
    const int total = BATCH * DIN;
    for (int gid = b * 256 + t; gid < total; gid += CONV_BLOCKS * 256) {
      int cf = gid % DIN;          // c*FEAT + f
      int c  = cf >> 9;            // /512
      float4 xv = ((const float4*)x)[gid];
      float4 wv = ((const float4*)W1)[c];
      float v = xv.x * wv.x + xv.y * wv.y + xv.z * wv.z + xv.w * wv.w + b1[c];
      flatA[gid] = f2bf(v);
    }
    return;
  }

  const float* in; unsigned short* outp; int R, Ncol, bx, by;
  if (b < CONV_BLOCKS + W2T_BLOCKS) {
    int idx = b - CONV_BLOCKS;
    in = W2; outp = W2T; R = DIN; Ncol = HIDDEN;
    bx = (idx & 15) * 64; by = (idx >> 4) * 64;
  } else {
    int idx = b - CONV_BLOCKS - W2T_BLOCKS;
    in = W3; outp = W3T; R = HIDDEN; Ncol = OUTPUT;
    bx = (idx & 3) * 64; by = (idx >> 2) * 64;
  }
  int tx = t & 63, ty = t >> 6;     // 4 rows per pass
  #pragma unroll
  for (int i = 0; i < 64; i += 4)
    tile[ty + i][tx] = in[(size_t)(by + ty + i) * Ncol + bx + tx];
  __syncthreads();
  #pragma unroll
  for (int i = 0; i < 64; i += 4)
    outp[(size_t)(bx + ty + i) * R + by + tx] = f2bf(tile[tx][ty + i]);
}

// ---------------------------------------------------------------------------
// Kernel 2: GEMM1, split-K=6, XCD swizzle, BK=32 (R3 body), PACKED epilogue.
// Cpart layout: [zt][rg = row>>2][col][r = row&3] bf16 -> each lane stores
// one ushort4 (4 row-values of one col) = 16 coalesced 8B stores/thread
// instead of 64 scattered 2B stores.
// ---------------------------------------------------------------------------
#define G1_BM 128
#define G1_BN 128
#define G1_BK 32
#define SPLITK 6
#define MN1 (BATCH * HIDDEN)

__global__ __launch_bounds__(256, 2) void gemm1_kernel(
    const unsigned short* __restrict__ A,   // [M,K]
    const unsigned short* __restrict__ BT,  // [N,K]
    unsigned short* __restrict__ Cp,        // packed partials
    int M, int N, int K)
{
  __shared__ unsigned short As[G1_BM * G1_BK];   // 8 KB
  __shared__ unsigned short Bs[G1_BN * G1_BK];   // 8 KB
  const int t    = threadIdx.x;
  const int lane = t & 63;
  const int wave = t >> 6;

  // swizzle decode: xcd group g owns M-tiles {2g, 2g+1}
  int b    = blockIdx.x;
  int xcdg = b & 7;
  int rest = b >> 3;          // 0..95
  int xt   = rest & 7;        // n-tile 0..7
  int zz   = rest >> 3;       // 0..11
  int zt   = zz >> 1;         // k-slice 0..5
  int yt   = (xcdg << 1) | (zz & 1);  // m-tile 0..15

  const int m0 = yt * G1_BM;
  const int n0 = xt * G1_BN;
  const int Ks = K / SPLITK;  // 1024
  const int kbeg = zt * Ks;

  const int wm = (wave >> 1) * 64;
  const int wn = (wave & 1) * 64;
  const int lm = lane & 15;
  const int kgrp = lane >> 4;
  const int lk = kgrp * 8;

  f32x4 acc[4][4];
  #pragma unroll
  for (int i = 0; i < 4; i++)
    #pragma unroll
    for (int j = 0; j < 4; j++) {
      f32x4 z = {0.f, 0.f, 0.f, 0.f};
      acc[i][j] = z;
    }

  const unsigned short* Ag = A  + (size_t)m0 * K + kbeg;
  const unsigned short* Bg = BT + (size_t)n0 * K + kbeg;

  for (int kk = 0; kk < Ks; kk += G1_BK) {
    #pragma unroll
    for (int r = 0; r < 2; ++r) {
      int chunk = r * 256 + t;
      int row = chunk >> 2;
      int kc  = (chunk & 3) * 8;
      async_copy16(Ag + (size_t)row * K + kk + kc, As + chunk * 8);
    }
    #pragma unroll
    for (int r = 0; r < 2; ++r) {
      int chunk = r * 256 + t;
      int row = chunk >> 2;
      int kc  = (chunk & 3) * 8;
      async_copy16(Bg + (size_t)row * K + kk + kc, Bs + chunk * 8);
    }
    __syncthreads();

    bf16x8 af[4], bfr[4];
    #pragma unroll
    for (int i = 0; i < 4; i++)
      af[i] = *(const bf16x8*)(As + (wm + i * 16 + lm) * G1_BK + lk);
    #pragma unroll
    for (int j = 0; j < 4; j++)
      bfr[j] = *(const bf16x8*)(Bs + (wn + j * 16 + lm) * G1_BK + lk);
    #pragma unroll
    for (int i = 0; i < 4; i++)
      #pragma unroll
      for (int j = 0; j < 4; j++)
        acc[i][j] = __builtin_amdgcn_mfma_f32_16x16x32_bf16(af[i], bfr[j], acc[i][j], 0, 0, 0);
    __syncthreads();
  }

  // packed epilogue: rg = (m0+wm+i*16+kgrp*4)>>2 = (m0+wm)/4 + i*4 + kgrp
  unsigned short* Co = Cp + (size_t)zt * MN1;
  const int rgbase = (m0 + wm) >> 2;
  #pragma unroll
  for (int i = 0; i < 4; i++) {
    int rg = rgbase + i * 4 + kgrp;
    #pragma unroll
    for (int j = 0; j < 4; j++) {
      int col = n0 + wn + j * 16 + lm;
      ushort4 o;
      o.x = f2bf(acc[i][j][0]);
      o.y = f2bf(acc[i][j][1]);
      o.z = f2bf(acc[i][j][2]);
      o.w = f2bf(acc[i][j][3]);
      *(ushort4*)(Co + ((size_t)rg * HIDDEN + col) * 4) = o;
    }
  }
}

// ---------------------------------------------------------------------------
// Kernel 3 (fused tail, 256 blocks): split-K reduce (packed, coalesced) +
// b2 + ReLU -> LDS h-stripe (16 rows), then h @ W3T + b3 -> out 16x128 tile.
// W3T fragments read straight from global (512 KB, L2-resident).
// ---------------------------------------------------------------------------
#define TB_M 16
#define HS_STRIDE (HIDDEN + 8)

__global__ __launch_bounds__(256) void tail_kernel(
    const unsigned short* __restrict__ Cp,   // packed partials
    const float* __restrict__ b2,
    const unsigned short* __restrict__ W3T,  // [OUTPUT][HIDDEN] bf16
    const float* __restrict__ b3,
    float* __restrict__ out)                 // [BATCH][OUTPUT] fp32
{
  __shared__ unsigned short hs[TB_M][HS_STRIDE];   // ~33 KB
  const int t = threadIdx.x;
  const int lane = t & 63;
  const int wave = t >> 6;
  const int bi = blockIdx.x >> 1;          // m-stripe 0..127
  const int nh = blockIdx.x & 1;           // col-half 0..1
  const int m0 = bi * TB_M;
  const int rg0 = m0 >> 2;                 // 4 row-groups per stripe

  // Phase 1: reduce 6 packed partials + bias + relu -> hs
  // slot = rg_local*1024 + col ; each thread handles 16 slots (ushort4 each)
  #pragma unroll
  for (int it = 0; it < 16; ++it) {
    int slot = it * 256 + t;
    int rgl = slot >> 10;
    int col = slot & (HIDDEN - 1);
    const unsigned short* p0 = Cp + ((size_t)(rg0 + rgl) * HIDDEN + col) * 4;
    float4 s = {0.f, 0.f, 0.f, 0.f};
    #pragma unroll
    for (int p = 0; p < SPLITK; ++p) {
      ushort4 a = *(const ushort4*)(p0 + (size_t)p * MN1);
      s.x += bf2f(a.x); s.y += bf2f(a.y); s.z += bf2f(a.z); s.w += bf2f(a.w);
    }
    float bb = b2[col];
    hs[rgl * 4 + 0][col] = f2bf(fmaxf(s.x + bb, 0.f));
    hs[rgl * 4 + 1][col] = f2bf(fmaxf(s.y + bb, 0.f));
    hs[rgl * 4 + 2][col] = f2bf(fmaxf(s.z + bb, 0.f));
    hs[rgl * 4 + 3][col] = f2bf(fmaxf(s.w + bb, 0.f));
  }
  __syncthreads();

  // Phase 2: hs[16][1024] @ W3T -> out rows m0..+15, cols nh*128 + wave*32..+31
  const int lm = lane & 15;
  const int kgrp = lane >> 4;
  const int ncol0 = nh * 128 + wave * 32;
  f32x4 acc[2];
  #pragma unroll
  for (int j = 0; j < 2; j++) {
    f32x4 z = {0.f, 0.f, 0.f, 0.f};
    acc[j] = z;
  }

  #pragma unroll 4
  for (int kk = 0; kk < HIDDEN; kk += 32) {
    bf16x8 af = *(const bf16x8*)(&hs[lm][kk + kgrp * 8]);
    #pragma unroll
    for (int j = 0; j < 2; j++) {
      const unsigned short* bp =
          W3T + (size_t)(ncol0 + j * 16 + lm) * HIDDEN + kk + kgrp * 8;
      bf16x8 bfr = *(const bf16x8*)bp;
      acc[j] = __builtin_amdgcn_mfma_f32_16x16x32_bf16(af, bfr, acc[j], 0, 0, 0);
    }
  }

  // epilogue: C/D layout col=lane&15, row=kgrp*4+reg
  #pragma unroll
  for (int j = 0; j < 2; j++) {
    int col = ncol0 + j * 16 + lm;
    float bias = b3[col];
    #pragma unroll
    for (int r = 0; r < 4; r++) {
      int row = m0 + kgrp * 4 + r;
      out[(size_t)row * OUTPUT + col] = acc[j][r] + bias;
    }
  }
}

// ---------------------------------------------------------------------------
extern "C" void kernel_launch(void* const* d_in, const int* in_sizes, int n_in,
                              void* d_out, int out_size, void* d_ws, size_t ws_size,
                              hipStream_t stream)
{
  const float* x  = (const float*)d_in[0];
  const float* W1 = (const float*)d_in[1];
  const float* b1 = (const float*)d_in[2];
  const float* W2 = (const float*)d_in[3];
  const float* b2 = (const float*)d_in[4];
  const float* W3 = (const float*)d_in[5];
  const float* b3 = (const float*)d_in[6];
  float* out = (float*)d_out;

  char* ws = (char*)d_ws;
  unsigned short* flatA = (unsigned short*)ws; ws += (size_t)BATCH * DIN * 2;
  unsigned short* W2T   = (unsigned short*)ws; ws += (size_t)HIDDEN * DIN * 2;
  unsigned short* W3T   = (unsigned short*)ws; ws += (size_t)OUTPUT * HIDDEN * 2;
  unsigned short* Cpart = (unsigned short*)ws; ws += (size_t)SPLITK * MN1 * 2;

  // 1. fused prep: conv (grid-stride) + W2/W3 transpose-casts
  prep_kernel<<<CONV_BLOCKS + W2T_BLOCKS + W3T_BLOCKS, 256, 0, stream>>>(
      x, W1, b1, flatA, W2, W2T, W3, W3T);
  // 2. GEMM1 split-K=6, XCD swizzle, BK=32, packed epilogue: 768 blocks
  gemm1_kernel<<<768, 256, 0, stream>>>(flatA, W2T, Cpart, BATCH, HIDDEN, DIN);
  // 3. fused tail (256 blocks): reduce + bias + relu + GEMM2 + bias -> out
  tail_kernel<<<2 * (BATCH / TB_M), 256, 0, stream>>>(Cpart, b2, W3T, b3, out);
}